// Round 14
// baseline (2447.655 us; speedup 1.0000x reference)
//
#include <hip/hip_runtime.h>
#include <stdint.h>

typedef unsigned short u16;
typedef short bf16x8 __attribute__((ext_vector_type(8)));
typedef float f32x4 __attribute__((ext_vector_type(4)));
typedef int i32x4 __attribute__((ext_vector_type(4)));

#define DEV static __device__ __forceinline__

constexpr int B_ = 512, T_ = 64, IN_ = 256, H_ = 512, V1_ = 101, P_ = 8, G4_ = 2048;
constexpr int EXR = 613;      // 101 embed rows + 512 x rows
constexpr int M_  = T_ * B_;  // 32768

DEV float b2f(u16 u) { union { uint32_t i; float f; } v; v.i = ((uint32_t)u) << 16; return v.f; }
DEV u16 f2b(float f) {
  union { float f; uint32_t i; } v; v.f = f;
  uint32_t i = v.i;
  return (u16)((i + 0x7fffu + ((i >> 16) & 1u)) >> 16);  // RNE
}
DEV float sigf(float x) { return 1.f / (1.f + __expf(-x)); }
DEV float tanh_(float x) {
  float c = fminf(fmaxf(x, -15.f), 15.f);
  float e = __expf(2.f * c);
  return (e - 1.f) / (e + 1.f);
}
DEV bf16x8 ld8(const u16* p) { return *reinterpret_cast<const bf16x8*>(p); }
DEV f32x4 mfma16(bf16x8 a, bf16x8 b, f32x4 c) {
  return __builtin_amdgcn_mfma_f32_16x16x32_bf16(a, b, c, 0, 0, 0);
}

// ---------------- fused f32 -> bf16 conversion over 9 segments ----------------
struct CvtArgs {
  const float* src[9];
  u16* dst[9];
  int pre[10];  // prefix sums in float4 units
};

__global__ __launch_bounds__(256) void k_cvtall(CvtArgs a) {
  int gid = blockIdx.x * 256 + threadIdx.x;
  if (gid >= a.pre[9]) return;
  int s = 0;
#pragma unroll
  for (int i = 1; i < 9; ++i) s += (gid >= a.pre[i]);
  const int local = gid - a.pre[s];
  const float4 v = reinterpret_cast<const float4*>(a.src[s])[local];
  ushort4 o;
  o.x = f2b(v.x); o.y = f2b(v.y); o.z = f2b(v.z); o.w = f2b(v.w);
  reinterpret_cast<ushort4*>(a.dst[s])[local] = o;
}

// ---------------- EX0 = [embed; x] @ w_ih0^T   (613 x 2048) bf16 ----------------
// bf16 output: halves the gather-add bytes and shrinks the hot set (rows 0..100) to
// 404 KB so it stays L2-resident on the L0-XCDs.
__global__ __launch_bounds__(256) void k_precomp(const u16* __restrict__ ex_src,
                                                 const u16* __restrict__ wih0b,
                                                 u16* __restrict__ EX0) {
  const int lane = threadIdx.x & 63;
  const int wv = threadIdx.x >> 6;
  const int m0 = blockIdx.x * 64 + wv * 16;
  const int n0 = blockIdx.y * 64;
  const int lr = lane & 15;
  const int lk = (lane >> 4) * 8;

  const int arow = m0 + lr;
  const bool valid = arow < EXR;

  f32x4 acc[4] = {};
  for (int k0 = 0; k0 < IN_; k0 += 32) {
    bf16x8 a = {};
    if (valid) a = ld8(ex_src + (size_t)arow * IN_ + k0 + lk);
#pragma unroll
    for (int c = 0; c < 4; ++c) {
      bf16x8 b = ld8(wih0b + (size_t)(n0 + c * 16 + lr) * IN_ + k0 + lk);
      acc[c] = mfma16(a, b, acc[c]);
    }
  }
  const int rb = (lane >> 4) * 4;
#pragma unroll
  for (int c = 0; c < 4; ++c)
#pragma unroll
    for (int r = 0; r < 4; ++r) {
      int row = m0 + rb + r;
      int col = n0 + c * 16 + (lane & 15);
      if (row < EXR) EX0[(size_t)row * G4_ + col] = f2b(acc[c][r]);
    }
}

// ---------------- LAYER-SPLIT + ROW-SHARD scan ----------------
// r13 lesson: per-XCD working set must fit 4MB L2 AND h must stay XCD-local.
// Layer-split does both: XCD x in 0..3 runs L0 for batch rows 128x..+127
// (working set: whh0 2MB + EX0-bf16 hot 0.4MB = 2.4MB, resident); XCD x in 4..7
// runs L1 for rows 128(x-4)..+127 (wih1+whh1 = 4MB, marginal). h0/h1 recurrences
// are XCD-local; only h0 crosses once to the paired L1 XCD (128KB/tick/XCD,
// L2-filled once, shared by its 32 blocks).
// Grid: 256 blocks x 512 thr (1 block/CU, 2 waves/SIMD). Block b: x=b&7, n=b>>3.
//   L0 (x<4):  rm=n&7 (16-row tile), cs=n>>3 (128-col slice). 8 waves = 8 col-16s.
//   L1 (x>=4): rm2=n&3 (32-row tile), cw=n>>2 (64-col slice). 8 waves = 2r x 4c.
// Flags: f0[x][rm][cs] (x<4: 4*8*4=128), f1[x4][rm2][cw] (128). Polls <=16 lanes.
// L0 step k: wait f0[x][rm][0..3]>=k; read h0[k]; write h0[k+1]; f0=k+1.
// L1 step k: wait f0[x4][2rm2..2rm2+1][*]>=k+1 and f1[x4][rm2][0..7]>=k;
//            read h0[k+1], h1[k]; write h1[k+1] (=outs[k]); f1=k+1.
// Correctness machinery (write-once slots, sc0/sc1 write-through, agent flags) is
// block->XCD-mapping independent; only speed relies on the %8 round-robin.
__global__ __launch_bounds__(512, 1) void k_scan(
    const u16* __restrict__ whh0, const u16* __restrict__ wih1, const u16* __restrict__ whh1,
    const u16* __restrict__ EX0, const int* __restrict__ y,
    u16* h0buf, u16* h1buf, unsigned* flags /* 256 u32, pre-zeroed */) {
  __shared__ u16 h0s[32 * 512];   // swizzled; L0 uses 16 rows, L1 uses 32
  __shared__ u16 h1s[32 * 512];   // L1 only
  __shared__ u16 stg[2048];       // 4KB write-out staging
  const size_t BH = (size_t)B_ * H_;
  const int tid = threadIdx.x;
  const int lane = tid & 63;
  const int wv = tid >> 6;               // 0..7
  const int x_ = blockIdx.x & 7;         // XCD (round-robin %8)
  const int n  = blockIdx.x >> 3;        // 0..31
  const bool isL1 = x_ >= 4;
  const int xr = x_ & 3;                 // row-shard index
  const int Rb = xr * 128;               // base batch row
  const int lr = lane & 15;
  const int lk = (lane >> 4) * 8;
  const int rb = (lane >> 4) * 4;

  // L0 decode
  const int rm = n & 7, cs = n >> 3;       // 16-row tile, 128-col slice
  // L1 decode
  const int rm2 = n & 3, cw = n >> 2;      // 32-row tile, 64-col slice

  int col, arow0;                          // output col; A-row base (local)
  if (!isL1) { col = cs * 128 + wv * 16 + lr; arow0 = 0; }
  else       { col = cw * 64 + (wv >> 1) * 16 + lr; arow0 = (wv & 1) * 16; }

  const u16* wpa[4]; const u16* wpb[4];
#pragma unroll
  for (int g = 0; g < 4; ++g) {
    wpa[g] = (isL1 ? wih1 : whh0) + (size_t)(g * H_ + col) * H_ + lk;
    wpb[g] = (isL1 ? whh1 : whh0) + (size_t)(g * H_ + col) * H_ + lk;
  }
  f32x4 cst = {};
  unsigned* f0g = flags + xr * 32 + (isL1 ? rm2 * 8 : rm * 4);  // L1: rows 2rm2,2rm2+1 = 8 flags
  unsigned* f1g = flags + 128 + xr * 32 + rm2 * 8;

  const int row0base = isL1 ? (Rb + rm2 * 32) : (Rb + rm * 16);
  const int nrows = isL1 ? 32 : 16;

  for (int k = 0; k < T_; ++k) {
    // ---- 1. flag wait ----
    if (wv == 0 && (k > 0 || isL1)) {
      unsigned thr = 0; const unsigned* ap = nullptr;
      if (!isL1) { if (lane < 4) { ap = f0g + lane; thr = (unsigned)k; } }
      else {
        if (lane < 8)       { ap = f0g + lane;     thr = (unsigned)(k + 1); }
        else if (lane < 16) { ap = f1g + lane - 8; thr = (unsigned)k; }
      }
      for (;;) {
        unsigned v = 0xffffffffu;
        if (ap) v = __hip_atomic_load(ap, __ATOMIC_RELAXED, __HIP_MEMORY_SCOPE_AGENT);
        if (__all(v >= thr)) break;
        __builtin_amdgcn_s_sleep(1);
      }
    }
    __syncthreads();

    // ---- 2. stage h tiles into swizzled LDS ----
    {
      const u16* h0g = h0buf + (size_t)(k + (isL1 ? 1 : 0)) * BH + (size_t)row0base * H_;
      const int nch = nrows * 64;          // 16B chunks
      for (int idx = tid; idx < nch; idx += 512) {
        const int row = idx >> 6, cc = idx & 63;
        i32x4 d = *(const i32x4*)(h0g + (size_t)row * H_ + cc * 8);
        *(i32x4*)((char*)h0s + row * 1024 + ((cc * 16) ^ ((row & 7) << 4))) = d;
      }
      if (isL1) {
        const u16* h1g = h1buf + (size_t)k * BH + (size_t)row0base * H_;
        for (int idx = tid; idx < nch; idx += 512) {
          const int row = idx >> 6, cc = idx & 63;
          i32x4 d = *(const i32x4*)(h1g + (size_t)row * H_ + cc * 8);
          *(i32x4*)((char*)h1s + row * 1024 + ((cc * 16) ^ ((row & 7) << 4))) = d;
        }
      }
    }
    __syncthreads();

    // ---- 3. compute ----
    if (!isL1) {  // L0: gates = h0(k)@whh0^T + EX0[srow] (bf16)
      f32x4 acc[4] = {};
#pragma unroll
      for (int i = 0; i < 16; ++i) {
        bf16x8 a0 = *(const bf16x8*)((const char*)h0s + lr * 1024 + (((i * 32 + lk) * 2) ^ ((lr & 7) << 4)));
#pragma unroll
        for (int g = 0; g < 4; ++g) acc[g] = mfma16(a0, ld8(wpa[g] + i * 32), acc[g]);
      }
      const int lcol = wv * 16 + lr;
#pragma unroll
      for (int r = 0; r < 4; ++r) {
        const int row = row0base + rb + r;
        const int srow = (k == 0) ? (V1_ + row) : y[row * T_ + k - 1];
        const u16* bp = EX0 + (size_t)srow * G4_ + col;
        float iv = acc[0][r] + b2f(bp[0]), fv = acc[1][r] + b2f(bp[H_]);
        float gv = acc[2][r] + b2f(bp[2 * H_]), ov = acc[3][r] + b2f(bp[3 * H_]);
        float cn = sigf(fv) * cst[r] + sigf(iv) * tanh_(gv);
        cst[r] = cn;
        stg[(rb + r) * 128 + lcol] = f2b(sigf(ov) * tanh_(cn));
      }
    } else {      // L1: gates = h0(k+1)@wih1^T + h1(k)@whh1^T
      f32x4 acc[4] = {};
#pragma unroll
      for (int i = 0; i < 16; ++i) {
        const int so = ((i * 32 + lk) * 2) ^ (((arow0 + lr) & 7) << 4);
        bf16x8 a0 = *(const bf16x8*)((const char*)h0s + (arow0 + lr) * 1024 + so);
        bf16x8 a1 = *(const bf16x8*)((const char*)h1s + (arow0 + lr) * 1024 + so);
#pragma unroll
        for (int g = 0; g < 4; ++g) {
          acc[g] = mfma16(a0, ld8(wpa[g] + i * 32), acc[g]);
          acc[g] = mfma16(a1, ld8(wpb[g] + i * 32), acc[g]);
        }
      }
      const int lcol = (wv >> 1) * 16 + lr;
#pragma unroll
      for (int r = 0; r < 4; ++r) {
        float cn = sigf(acc[1][r]) * cst[r] + sigf(acc[0][r]) * tanh_(acc[2][r]);
        cst[r] = cn;
        stg[(arow0 + rb + r) * 64 + lcol] = f2b(sigf(acc[3][r]) * tanh_(cn));
      }
    }
    __syncthreads();

    // ---- 4. write-out (sc0/sc1 write-through) ----
    if (tid < 256) {
      if (!isL1) {
        const int lrow = tid >> 4, c8 = (tid & 15) * 8;   // 16 rows x 128 cols
        i32x4 d = *(const i32x4*)&stg[lrow * 128 + c8];
        u16* gp = h0buf + (size_t)(k + 1) * BH + (size_t)(row0base + lrow) * H_ + cs * 128 + c8;
        asm volatile("global_store_dwordx4 %0, %1, off sc0 sc1" :: "v"(gp), "v"(d) : "memory");
      } else {
        const int lrow = tid >> 3, c8 = (tid & 7) * 8;    // 32 rows x 64 cols
        i32x4 d = *(const i32x4*)&stg[lrow * 64 + c8];
        u16* gp = h1buf + (size_t)(k + 1) * BH + (size_t)(row0base + lrow) * H_ + cw * 64 + c8;
        asm volatile("global_store_dwordx4 %0, %1, off sc0 sc1" :: "v"(gp), "v"(d) : "memory");
      }
    }
    asm volatile("s_waitcnt vmcnt(0)" ::: "memory");
    __syncthreads();
    // ---- 5. arrive ----
    if (tid == 0) {
      unsigned* fa = isL1 ? &f1g[cw] : &f0g[cs];
      __hip_atomic_store(fa, (unsigned)(k + 1), __ATOMIC_RELAXED, __HIP_MEMORY_SCOPE_AGENT);
    }
  }
}

// ---------------- feat1 = relu(outs@l1w^T+l1b), pf1 = relu(outs@r1w^T+r1b) ----------------
__global__ __launch_bounds__(256) void k_fused1(const u16* __restrict__ outs,
                                                const u16* __restrict__ l1w, const float* __restrict__ l1b,
                                                const u16* __restrict__ r1w, const float* __restrict__ r1b,
                                                u16* __restrict__ feat1, u16* __restrict__ pf1) {
  const int lane = threadIdx.x & 63;
  const int wv = threadIdx.x >> 6;
  const int lr = lane & 15;
  const int lk = (lane >> 4) * 8;
  const int ar = blockIdx.x * 64 + wv * 16 + lr;
  const int rb = (lane >> 4) * 4;
  const int row0 = blockIdx.x * 64 + wv * 16 + rb;

  bf16x8 a[16];
  {
    const u16* ap = outs + (size_t)ar * H_ + lk;
#pragma unroll
    for (int i = 0; i < 16; ++i) a[i] = ld8(ap + i * 32);
  }
  for (int w = 0; w < 2; ++w) {
    const u16* W = w ? r1w : l1w;
    const float* bias = w ? r1b : l1b;
    u16* dst = w ? pf1 : feat1;
    for (int nc = 0; nc < 4; ++nc) {
      f32x4 acc[8] = {};
#pragma unroll
      for (int i = 0; i < 16; ++i)
#pragma unroll
        for (int nn = 0; nn < 8; ++nn)
          acc[nn] = mfma16(a[i], ld8(W + (size_t)(nc * 128 + nn * 16 + lr) * H_ + i * 32 + lk), acc[nn]);
#pragma unroll
      for (int nn = 0; nn < 8; ++nn) {
        const int colc = nc * 128 + nn * 16 + lr;
        const float bv = bias[colc];
#pragma unroll
        for (int r = 0; r < 4; ++r)
          dst[(size_t)(row0 + r) * H_ + colc] = f2b(fmaxf(acc[nn][r] + bv, 0.f));
      }
    }
  }
}

// ---------------- feat2 + log_softmax (pgm out) + softmax + param head ----------------
__global__ __launch_bounds__(256) void k_fused2(const u16* __restrict__ feat1,
                                                const u16* __restrict__ l2w, const float* __restrict__ l2b,
                                                const u16* __restrict__ pf1,
                                                const float* __restrict__ r2w, const float* __restrict__ r2b,
                                                const int* __restrict__ y,
                                                float* __restrict__ pgm, float* __restrict__ par) {
  __shared__ float trans[64][104];
  const int lane = threadIdx.x & 63;
  const int wv = threadIdx.x >> 6;
  const int lr = lane & 15;
  const int lk = (lane >> 4) * 8;
  const int ar = blockIdx.x * 64 + wv * 16 + lr;
  const int rb = (lane >> 4) * 4;

  f32x4 acc[7] = {};
  {
    const u16* ap = feat1 + (size_t)ar * H_ + lk;
#pragma unroll
    for (int i = 0; i < 16; ++i) {
      bf16x8 av = ld8(ap + i * 32);
#pragma unroll
      for (int c = 0; c < 7; ++c) {
        const int nn = c * 16 + lr;
        bf16x8 b = {};
        if (nn < V1_) b = ld8(l2w + (size_t)nn * H_ + i * 32 + lk);
        acc[c] = mfma16(av, b, acc[c]);
      }
    }
  }
#pragma unroll
  for (int r = 0; r < 4; ++r) {
    float v[7];
    float mx = -1e30f;
#pragma unroll
    for (int c = 0; c < 7; ++c) {
      const int colc = c * 16 + lr;
      v[c] = (colc < V1_) ? acc[c][r] + l2b[colc] : -1e30f;
      mx = fmaxf(mx, v[c]);
    }
#pragma unroll
    for (int o = 1; o < 16; o <<= 1) mx = fmaxf(mx, __shfl_xor(mx, o, 64));
    float e[7], s = 0.f;
#pragma unroll
    for (int c = 0; c < 7; ++c) { e[c] = (c * 16 + lr < V1_) ? __expf(v[c] - mx) : 0.f; s += e[c]; }
#pragma unroll
    for (int o = 1; o < 16; o <<= 1) s += __shfl_xor(s, o, 64);
    const float lz = __logf(s), inv = 1.f / s;
    const int m = blockIdx.x * 64 + wv * 16 + rb + r;
    const int t = m >> 9, bb = m & 511;
    float* po = pgm + ((size_t)bb * T_ + t) * V1_;
#pragma unroll
    for (int c = 0; c < 7; ++c) {
      const int colc = c * 16 + lr;
      if (colc < V1_) { po[colc] = v[c] - mx - lz; trans[wv * 16 + rb + r][colc] = e[c] * inv; }
    }
  }
  __syncthreads();
  for (int rr = 0; rr < 16; ++rr) {
    const int m = blockIdx.x * 64 + wv * 16 + rr;
    const int t = m >> 9, bb = m & 511;
    const int idx = y[bb * T_ + t];
    const float* wb = r2w + (size_t)idx * P_ * 613;
    float a8[P_] = {};
    for (int kk = lane; kk < 613; kk += 64) {
      float xv = (kk < V1_) ? trans[wv * 16 + rr][kk] : b2f(pf1[(size_t)m * H_ + kk - V1_]);
#pragma unroll
      for (int p = 0; p < P_; ++p) a8[p] += xv * wb[(size_t)p * 613 + kk];
    }
#pragma unroll
    for (int p = 0; p < P_; ++p)
#pragma unroll
      for (int o = 1; o < 64; o <<= 1) a8[p] += __shfl_xor(a8[p], o, 64);
    if (lane < P_) par[((size_t)bb * T_ + t) * P_ + lane] = a8[lane] + r2b[idx * P_ + lane];
  }
}

extern "C" void kernel_launch(void* const* d_in, const int* in_sizes, int n_in,
                              void* d_out, int out_size, void* d_ws, size_t ws_size,
                              hipStream_t stream) {
  (void)in_sizes; (void)n_in; (void)out_size; (void)ws_size;
  const float* x     = (const float*)d_in[0];
  const int*   y     = (const int*)d_in[1];
  const float* embed = (const float*)d_in[2];
  const float* wih0  = (const float*)d_in[3];
  const float* whh0  = (const float*)d_in[4];
  const float* wih1  = (const float*)d_in[5];
  const float* whh1  = (const float*)d_in[6];
  const float* l1w   = (const float*)d_in[7];
  const float* l1b   = (const float*)d_in[8];
  const float* l2w   = (const float*)d_in[9];
  const float* l2b   = (const float*)d_in[10];
  const float* r1w   = (const float*)d_in[11];
  const float* r1b   = (const float*)d_in[12];
  const float* r2w   = (const float*)d_in[13];
  const float* r2b   = (const float*)d_in[14];

  float* out_pgm = (float*)d_out;
  float* out_par = out_pgm + (size_t)B_ * T_ * V1_;

  char* ws = (char*)d_ws;
  size_t off = 0;
  auto alloc = [&](size_t bytes) { void* p = ws + off; off += (bytes + 255) & ~(size_t)255; return p; };

  const size_t BH2 = (size_t)B_ * H_ * 2;  // one slot, bytes (512 KB)

  // [flags | h0buf slot0..] contiguous -> first memset covers flags + h0 slot 0
  unsigned* flags = (unsigned*)alloc(256 * 4);             // 1 KB: f0[128] | f1[128]
  u16* h0buf  = (u16*)alloc((size_t)(T_ + 1) * BH2);       // 65 write-once slots
  u16* h1buf  = (u16*)alloc((size_t)(T_ + 1) * BH2);       // 65 write-once slots (1..64 = outs)

  u16* EX0b    = (u16*)alloc((size_t)EXR * G4_ * 2);       // bf16 EX0
  u16* ex_src  = (u16*)alloc((size_t)EXR * IN_ * 2);
  u16* wih0b   = (u16*)alloc((size_t)4 * H_ * IN_ * 2);
  u16* whh0b   = (u16*)alloc((size_t)4 * H_ * H_ * 2);
  u16* wih1b   = (u16*)alloc((size_t)4 * H_ * H_ * 2);
  u16* whh1b   = (u16*)alloc((size_t)4 * H_ * H_ * 2);
  u16* l1wb    = (u16*)alloc((size_t)H_ * H_ * 2);
  u16* r1wb    = (u16*)alloc((size_t)H_ * H_ * 2);
  u16* l2wb    = (u16*)alloc((size_t)V1_ * H_ * 2);
  u16* feat1   = (u16*)alloc((size_t)M_ * H_ * 2);
  u16* pf1     = (u16*)alloc((size_t)M_ * H_ * 2);

  (void)hipMemsetAsync(flags, 0, 256 * 4 + BH2, stream);   // flags + h0buf slot 0
  (void)hipMemsetAsync(h1buf, 0, BH2, stream);             // h1buf slot 0

  CvtArgs ca;
  const float* srcs[9] = {embed, x, wih0, whh0, wih1, whh1, l1w, r1w, l2w};
  u16* dsts[9] = {ex_src, ex_src + (size_t)V1_ * IN_, wih0b, whh0b, wih1b, whh1b, l1wb, r1wb, l2wb};
  int ns[9] = {V1_ * IN_, B_ * IN_, 4 * H_ * IN_, 4 * H_ * H_, 4 * H_ * H_, 4 * H_ * H_,
               H_ * H_, H_ * H_, V1_ * H_};
  int acc4 = 0;
  for (int i = 0; i < 9; ++i) {
    ca.src[i] = srcs[i]; ca.dst[i] = dsts[i]; ca.pre[i] = acc4; acc4 += ns[i] / 4;
  }
  ca.pre[9] = acc4;
  k_cvtall<<<(acc4 + 255) / 256, 256, 0, stream>>>(ca);

  k_precomp<<<dim3(10, 32), 256, 0, stream>>>(ex_src, wih0b, EX0b);

  k_scan<<<256, 512, 0, stream>>>(whh0b, wih1b, whh1b, EX0b, y, h0buf, h1buf, flags);

  u16* outs = h1buf + (size_t)B_ * H_;  // slots 1..64 = h1 after steps 0..63 = outs[T][B][H]
  k_fused1<<<512, 256, 0, stream>>>(outs, l1wb, l1b, r1wb, r1b, feat1, pf1);
  k_fused2<<<512, 256, 0, stream>>>(feat1, l2wb, l2b, pf1, r2w, r2b, y, out_pgm, out_par);
}